// Round 8
// baseline (207.827 us; speedup 1.0000x reference)
//
#include <hip/hip_runtime.h>
#include <hip/hip_bf16.h>
#include <math.h>

#define BB 2
#define LL 2048
#define EE 512
#define HH 8
#define DD 64
#define MM (BB * LL)   // 4096
#define LW (LL / 64)   // 32 k-tiles of 64

typedef short bf16x8 __attribute__((ext_vector_type(8)));   // 8 bf16 = 4 VGPRs
typedef float f32x4 __attribute__((ext_vector_type(4)));

#define MFMA16(a, b, c) __builtin_amdgcn_mfma_f32_16x16x32_bf16((a), (b), (c), 0, 0, 0)

#if __has_builtin(__builtin_amdgcn_exp2f)
#define EXP2(x) __builtin_amdgcn_exp2f(x)
#else
#define EXP2(x) exp2f(x)
#endif

// q-scale with log2(e) folded: (1/sqrt(512)) * log2(e)
#define QSCALE 0.0637587146f

__device__ __forceinline__ uint4 cvt8_bf16(const float4 a, const float4 b) {
    union { __hip_bfloat16 h[8]; uint4 u; } t;
    t.h[0] = __float2bfloat16(a.x); t.h[1] = __float2bfloat16(a.y);
    t.h[2] = __float2bfloat16(a.z); t.h[3] = __float2bfloat16(a.w);
    t.h[4] = __float2bfloat16(b.x); t.h[5] = __float2bfloat16(b.y);
    t.h[6] = __float2bfloat16(b.z); t.h[7] = __float2bfloat16(b.w);
    return t.u;
}

// ---------------------------------------------------------------------------
// prep: X cvt (3072 blks), W cvt (512 blks), mask ballot grid-strided:
// 2048 blks x 16 rounds x 256 thr = 8,388,608 = BB*LL*LL exactly.
// ---------------------------------------------------------------------------
struct PrepArgs {
    const float* xsrc[3];
    __hip_bfloat16* xdst[3];
    const float* wsrc[4];
    __hip_bfloat16* wdst[4];
    const int* mask;
    unsigned long long* mbits;
};

__global__ __launch_bounds__(256) void prep(PrepArgs a) {
    const int blk = blockIdx.x;
    if (blk < 3072) {
        const int t = blk >> 10;
        const int i = ((blk & 1023) * 256 + threadIdx.x) * 8;
        const float* s = a.xsrc[t] + i;
        float4 f0 = *(const float4*)(s);
        float4 f1 = *(const float4*)(s + 4);
        *(uint4*)(a.xdst[t] + i) = cvt8_bf16(f0, f1);
    } else if (blk < 3584) {
        const int r = blk - 3072;
        const int t = r >> 7;
        const int i = ((r & 127) * 256 + threadIdx.x) * 8;
        const float* s = a.wsrc[t] + i;
        float4 f0 = *(const float4*)(s);
        float4 f1 = *(const float4*)(s + 4);
        *(uint4*)(a.wdst[t] + i) = cvt8_bf16(f0, f1);
    } else {
        const int mb = blk - 3584;   // 0..2047, 16 rounds each
        #pragma unroll
        for (int r = 0; r < 16; ++r) {
            const size_t idx = ((size_t)mb * 16 + r) * 256 + threadIdx.x;
            const int m = a.mask[idx];
            const unsigned long long w = __ballot(m != 0);
            if ((threadIdx.x & 63) == 0) a.mbits[idx >> 6] = w;
        }
    }
}

// ---------------------------------------------------------------------------
// V [B,L,E](bf16) -> V^T [B,H,D,L](bf16). LDS-tiled.
// ---------------------------------------------------------------------------
__global__ __launch_bounds__(256) void transpose_v(
    const __hip_bfloat16* __restrict__ vb, __hip_bfloat16* __restrict__ vt) {
    __shared__ __hip_bfloat16 T[64][72];
    const int tid = threadIdx.x;
    const int l0 = blockIdx.x * 64;
    const int h = blockIdx.y;
    const int b = blockIdx.z;
    const int row = tid >> 2;
    const int cg = (tid & 3) * 16;

    const __hip_bfloat16* src = vb + ((size_t)b * LL + l0 + row) * EE + h * DD + cg;
    *(uint4*)&T[row][cg] = *(const uint4*)src;
    *(uint4*)&T[row][cg + 8] = *(const uint4*)(src + 8);
    __syncthreads();

    __hip_bfloat16 t[16];
    #pragma unroll
    for (int e = 0; e < 16; ++e) t[e] = T[cg + e][row];
    __hip_bfloat16* dst = vt + (((size_t)b * HH + h) * DD + row) * LL + l0 + cg;
    *(uint4*)&dst[0] = *(uint4*)&t[0];
    *(uint4*)&dst[8] = *(uint4*)&t[8];
}

// ---------------------------------------------------------------------------
// NO-LDS, NO-BARRIER bf16 GEMM: C[M,N] = X[M,512] @ W[N,512]^T + bias.
// Each wave independently computes a 32(M) x 64(N) tile; MFMA fragments are
// loaded DIRECTLY from global (lane l15 = row, 16B at col quad*8): per
// 32-wide K-chunk, 6 global_load_dwordx4 + 8 MFMA, zero __syncthreads.
// The compiler software-pipelines via vmcnt(N) across chunks. W rows are
// L2-hot (0.5 MB). Block = 4 waves = 128M x 64N.
// ---------------------------------------------------------------------------
struct QKVArgs {
    const __hip_bfloat16* X[3];
    const __hip_bfloat16* W[3];
    const float* bias[3];
    __hip_bfloat16* O[3];
};

__global__ __launch_bounds__(256) void gemm_qkv(QKVArgs p) {
    const int z = blockIdx.z;
    const __hip_bfloat16* __restrict__ X = p.X[z];
    const __hip_bfloat16* __restrict__ W = p.W[z];
    const float* __restrict__ bias = p.bias[z];
    __hip_bfloat16* __restrict__ O = p.O[z];
    const float oscale = (z == 0) ? QSCALE : 1.0f;   // fold scale*log2e into q

    const int tid = threadIdx.x;
    const int wave = tid >> 6, lane = tid & 63;
    const int l15 = lane & 15, quad = lane >> 4;
    const int mw = blockIdx.y * 128 + wave * 32;     // wave's M base
    const int n0 = blockIdx.x * 64;                  // wave's N base

    const __hip_bfloat16* Arow = X + (size_t)(mw + l15) * EE + quad * 8;
    const __hip_bfloat16* Brow = W + (size_t)(n0 + l15) * EE + quad * 8;

    f32x4 acc[2][4] = {};

    #pragma unroll 4
    for (int k0 = 0; k0 < EE; k0 += 32) {
        bf16x8 a0 = *(const bf16x8*)(Arow + k0);
        bf16x8 a1 = *(const bf16x8*)(Arow + (size_t)16 * EE + k0);
        bf16x8 b0 = *(const bf16x8*)(Brow + k0);
        bf16x8 b1 = *(const bf16x8*)(Brow + (size_t)16 * EE + k0);
        bf16x8 b2 = *(const bf16x8*)(Brow + (size_t)32 * EE + k0);
        bf16x8 b3 = *(const bf16x8*)(Brow + (size_t)48 * EE + k0);
        acc[0][0] = MFMA16(a0, b0, acc[0][0]);
        acc[0][1] = MFMA16(a0, b1, acc[0][1]);
        acc[0][2] = MFMA16(a0, b2, acc[0][2]);
        acc[0][3] = MFMA16(a0, b3, acc[0][3]);
        acc[1][0] = MFMA16(a1, b0, acc[1][0]);
        acc[1][1] = MFMA16(a1, b1, acc[1][1]);
        acc[1][2] = MFMA16(a1, b2, acc[1][2]);
        acc[1][3] = MFMA16(a1, b3, acc[1][3]);
    }

    #pragma unroll
    for (int i = 0; i < 2; ++i)
        #pragma unroll
        for (int j = 0; j < 4; ++j) {
            const int n = n0 + j * 16 + l15;
            const float bv = bias[n];
            #pragma unroll
            for (int reg = 0; reg < 4; ++reg) {
                const int m = mw + i * 16 + quad * 4 + reg;
                O[(size_t)m * EE + n] = __float2bfloat16((acc[i][j][reg] + bv) * oscale);
            }
        }
}

__global__ __launch_bounds__(256) void gemm_out(
    const __hip_bfloat16* __restrict__ X, const __hip_bfloat16* __restrict__ W,
    const float* __restrict__ bias, float* __restrict__ C) {
    const int tid = threadIdx.x;
    const int wave = tid >> 6, lane = tid & 63;
    const int l15 = lane & 15, quad = lane >> 4;
    const int mw = blockIdx.y * 128 + wave * 32;
    const int n0 = blockIdx.x * 64;

    const __hip_bfloat16* Arow = X + (size_t)(mw + l15) * EE + quad * 8;
    const __hip_bfloat16* Brow = W + (size_t)(n0 + l15) * EE + quad * 8;

    f32x4 acc[2][4] = {};

    #pragma unroll 4
    for (int k0 = 0; k0 < EE; k0 += 32) {
        bf16x8 a0 = *(const bf16x8*)(Arow + k0);
        bf16x8 a1 = *(const bf16x8*)(Arow + (size_t)16 * EE + k0);
        bf16x8 b0 = *(const bf16x8*)(Brow + k0);
        bf16x8 b1 = *(const bf16x8*)(Brow + (size_t)16 * EE + k0);
        bf16x8 b2 = *(const bf16x8*)(Brow + (size_t)32 * EE + k0);
        bf16x8 b3 = *(const bf16x8*)(Brow + (size_t)48 * EE + k0);
        acc[0][0] = MFMA16(a0, b0, acc[0][0]);
        acc[0][1] = MFMA16(a0, b1, acc[0][1]);
        acc[0][2] = MFMA16(a0, b2, acc[0][2]);
        acc[0][3] = MFMA16(a0, b3, acc[0][3]);
        acc[1][0] = MFMA16(a1, b0, acc[1][0]);
        acc[1][1] = MFMA16(a1, b1, acc[1][1]);
        acc[1][2] = MFMA16(a1, b2, acc[1][2]);
        acc[1][3] = MFMA16(a1, b3, acc[1][3]);
    }

    #pragma unroll
    for (int i = 0; i < 2; ++i)
        #pragma unroll
        for (int j = 0; j < 4; ++j) {
            const int n = n0 + j * 16 + l15;
            const float bv = bias[n];
            #pragma unroll
            for (int reg = 0; reg < 4; ++reg) {
                const int m = mw + i * 16 + quad * 4 + reg;
                C[(size_t)m * EE + n] = acc[i][j][reg] + bv;
            }
        }
}

// ---------------------------------------------------------------------------
// Flash attention, bf16 MFMA, S^T = K Q^T, no-max softmax with exp2 (log2e
// folded into q via QSCALE in the projection). r5-style register-prefetch
// double-buffered K/V staging (beats global_load_lds here: no vmcnt(0)
// drain at the barrier). ALL LDS row strides = 68 shorts (34 dwords,
// gcd(34,32)=2 -> 2-way max = free) -- fixes the constant 5.77M conflicts.
// ---------------------------------------------------------------------------
__global__ __launch_bounds__(256) void attn_mfma(
    const __hip_bfloat16* __restrict__ Qb, const __hip_bfloat16* __restrict__ Kb,
    const __hip_bfloat16* __restrict__ vtg, const unsigned long long* __restrict__ mbits,
    __hip_bfloat16* __restrict__ Op) {
    __shared__ __hip_bfloat16 Ks[2][64][68];
    __shared__ __hip_bfloat16 Vs[2][64][68];
    __shared__ __hip_bfloat16 Ps[4][16][68];

    const int tid = threadIdx.x;
    const int wave = tid >> 6;
    const int lane = tid & 63;
    const int l15 = lane & 15;
    const int quad = lane >> 4;
    const int b = blockIdx.z;
    const int h = blockIdx.y;
    const int q0 = blockIdx.x * 64;
    const int myq = q0 + wave * 16 + l15;

    const int srow = tid >> 2;        // 0..63
    const int scg = (tid & 3) * 16;   // 0,16,32,48

    // Q fragments (B operand), pre-scaled by QSCALE in the projection
    bf16x8 qf[2];
    {
        const __hip_bfloat16* qrow = Qb + ((size_t)b * LL + myq) * EE + h * DD;
        qf[0] = *(const bf16x8*)(qrow + quad * 8);
        qf[1] = *(const bf16x8*)(qrow + 32 + quad * 8);
    }

    const __hip_bfloat16* kbase = Kb + ((size_t)b * LL + srow) * EE + h * DD + scg;
    const __hip_bfloat16* vbase = vtg + (((size_t)b * HH + h) * DD + srow) * LL + scg;
    const unsigned long long* mrow = mbits + ((size_t)b * LL + myq) * LW;

    f32x4 o[4] = {};
    float lrun = 0.f;

    // stage tile 0 into buffer 0
    {
        uint4 k0a = *(const uint4*)(kbase);
        uint4 k0b = *(const uint4*)(kbase + 8);
        uint4 v0a = *(const uint4*)(vbase);
        uint4 v0b = *(const uint4*)(vbase + 8);
        *(uint4*)&Ks[0][srow][scg] = k0a;
        *(uint4*)&Ks[0][srow][scg + 8] = k0b;
        *(uint4*)&Vs[0][srow][scg] = v0a;
        *(uint4*)&Vs[0][srow][scg + 8] = v0b;
    }
    unsigned long long mw_cur = mrow[0];
    __syncthreads();

    for (int t = 0; t < LW; ++t) {
        const int cur = t & 1;
        const int nxt = cur ^ 1;
        const bool more = (t + 1) < LW;

        // prefetch next tile into registers (lands during compute)
        uint4 ka0, ka1, va0, va1;
        unsigned long long mw_n;
        if (more) {
            const __hip_bfloat16* kn = kbase + (size_t)(t + 1) * 64 * EE;
            const __hip_bfloat16* vn = vbase + (t + 1) * 64;
            ka0 = *(const uint4*)(kn);
            ka1 = *(const uint4*)(kn + 8);
            va0 = *(const uint4*)(vn);
            va1 = *(const uint4*)(vn + 8);
            mw_n = mrow[t + 1];
        }

        // ---- S^T = K (Q*scale*log2e)^T ----
        f32x4 st[4] = {};
        #pragma unroll
        for (int mt = 0; mt < 4; ++mt) {
            bf16x8 a0 = *(const bf16x8*)&Ks[cur][mt * 16 + l15][quad * 8];
            bf16x8 a1 = *(const bf16x8*)&Ks[cur][mt * 16 + l15][32 + quad * 8];
            st[mt] = MFMA16(a0, qf[0], st[mt]);
            st[mt] = MFMA16(a1, qf[1], st[mt]);
        }

        // ---- no-max softmax: p = live ? exp2(logit) : 0 ----
        #pragma unroll
        for (int mt = 0; mt < 4; ++mt) {
            float p[4];
            #pragma unroll
            for (int reg = 0; reg < 4; ++reg) {
                const bool live = (mw_cur >> (mt * 16 + quad * 4 + reg)) & 1ull;
                const float e = EXP2(st[mt][reg]);
                p[reg] = live ? e : 0.f;
                lrun += p[reg];
            }
            union { __hip_bfloat16 hh[4]; ushort4 v; } pk;
            pk.hh[0] = __float2bfloat16(p[0]);
            pk.hh[1] = __float2bfloat16(p[1]);
            pk.hh[2] = __float2bfloat16(p[2]);
            pk.hh[3] = __float2bfloat16(p[3]);
            *(ushort4*)&Ps[wave][l15][mt * 16 + quad * 4] = pk.v;
        }

        // ---- O += P V (wave-private strip, no barrier) ----
        bf16x8 pa0 = *(const bf16x8*)&Ps[wave][l15][quad * 8];
        bf16x8 pa1 = *(const bf16x8*)&Ps[wave][l15][32 + quad * 8];
        #pragma unroll
        for (int nt = 0; nt < 4; ++nt) {
            bf16x8 vb0 = *(const bf16x8*)&Vs[cur][nt * 16 + l15][quad * 8];
            bf16x8 vb1 = *(const bf16x8*)&Vs[cur][nt * 16 + l15][32 + quad * 8];
            o[nt] = MFMA16(pa0, vb0, o[nt]);
            o[nt] = MFMA16(pa1, vb1, o[nt]);
        }

        // ---- commit prefetched tile to the other buffer ----
        if (more) {
            *(uint4*)&Ks[nxt][srow][scg] = ka0;
            *(uint4*)&Ks[nxt][srow][scg + 8] = ka1;
            *(uint4*)&Vs[nxt][srow][scg] = va0;
            *(uint4*)&Vs[nxt][srow][scg + 8] = va1;
            mw_cur = mw_n;
        }
        __syncthreads();
    }

    // ---- reduce l across quads once, finalize ----
    lrun += __shfl_xor(lrun, 16);
    lrun += __shfl_xor(lrun, 32);
    const float linv = 1.f / lrun;
    float linvR[4];
    #pragma unroll
    for (int reg = 0; reg < 4; ++reg)
        linvR[reg] = __shfl(linv, quad * 4 + reg);

    __hip_bfloat16* Ob = Op + ((size_t)b * LL + q0 + wave * 16) * EE + h * DD;
    #pragma unroll
    for (int nt = 0; nt < 4; ++nt)
        #pragma unroll
        for (int reg = 0; reg < 4; ++reg) {
            const int qrow = quad * 4 + reg;
            Ob[(size_t)qrow * EE + nt * 16 + l15] =
                __float2bfloat16(o[nt][reg] * linvR[reg]);
        }
}

// ---------------------------------------------------------------------------
extern "C" void kernel_launch(void* const* d_in, const int* in_sizes, int n_in,
                              void* d_out, int out_size, void* d_ws, size_t ws_size,
                              hipStream_t stream) {
    const float* values = (const float*)d_in[0];
    const float* keys   = (const float*)d_in[1];
    const float* query  = (const float*)d_in[2];
    const int*   mask   = (const int*)d_in[3];
    const float* Wv = (const float*)d_in[4];
    const float* bv = (const float*)d_in[5];
    const float* Wk = (const float*)d_in[6];
    const float* bk = (const float*)d_in[7];
    const float* Wq = (const float*)d_in[8];
    const float* bq = (const float*)d_in[9];
    const float* Wo = (const float*)d_in[10];
    const float* bo = (const float*)d_in[11];
    float* out = (float*)d_out;

    const size_t XS = (size_t)MM * EE * 2;   // 4 MB bf16 [4096,512]
    const size_t WS = (size_t)EE * EE * 2;   // 0.5 MB bf16 [512,512]
    char* w = (char*)d_ws;
    __hip_bfloat16* xq  = (__hip_bfloat16*)(w);
    __hip_bfloat16* xk  = (__hip_bfloat16*)(w + XS);
    __hip_bfloat16* xv  = (__hip_bfloat16*)(w + 2 * XS);
    __hip_bfloat16* qb  = (__hip_bfloat16*)(w + 3 * XS);
    __hip_bfloat16* kb  = (__hip_bfloat16*)(w + 4 * XS);
    __hip_bfloat16* vb  = (__hip_bfloat16*)(w + 5 * XS);
    __hip_bfloat16* vtg = (__hip_bfloat16*)(w + 6 * XS);
    __hip_bfloat16* aob = (__hip_bfloat16*)(w + 7 * XS);
    __hip_bfloat16* wqb = (__hip_bfloat16*)(w + 8 * XS);
    __hip_bfloat16* wkb = (__hip_bfloat16*)(w + 8 * XS + WS);
    __hip_bfloat16* wvb = (__hip_bfloat16*)(w + 8 * XS + 2 * WS);
    __hip_bfloat16* wob = (__hip_bfloat16*)(w + 8 * XS + 3 * WS);
    unsigned long long* mbits = (unsigned long long*)(w + 8 * XS + 4 * WS);

    PrepArgs pa;
    pa.xsrc[0] = query; pa.xsrc[1] = keys; pa.xsrc[2] = values;
    pa.xdst[0] = xq;    pa.xdst[1] = xk;   pa.xdst[2] = xv;
    pa.wsrc[0] = Wq; pa.wsrc[1] = Wk; pa.wsrc[2] = Wv; pa.wsrc[3] = Wo;
    pa.wdst[0] = wqb; pa.wdst[1] = wkb; pa.wdst[2] = wvb; pa.wdst[3] = wob;
    pa.mask = mask; pa.mbits = mbits;

    QKVArgs qa;
    qa.X[0] = xq;  qa.X[1] = xk;  qa.X[2] = xv;
    qa.W[0] = wqb; qa.W[1] = wkb; qa.W[2] = wvb;
    qa.bias[0] = bq; qa.bias[1] = bk; qa.bias[2] = bv;
    qa.O[0] = qb;  qa.O[1] = kb;  qa.O[2] = vb;

    prep<<<5632, 256, 0, stream>>>(pa);
    gemm_qkv<<<dim3(EE / 64, MM / 128, 3), 256, 0, stream>>>(qa);
    transpose_v<<<dim3(LL / 64, HH, BB), 256, 0, stream>>>(vb, vtg);
    attn_mfma<<<dim3(LL / 64, HH, BB), 256, 0, stream>>>(qb, kb, vtg, mbits, aob);
    gemm_out<<<dim3(EE / 64, MM / 128), 256, 0, stream>>>(aob, wob, bo, out);
}

// Round 9
// 186.283 us; speedup vs baseline: 1.1157x; 1.1157x over previous
//
#include <hip/hip_runtime.h>
#include <hip/hip_bf16.h>
#include <math.h>

#define BB 2
#define LL 2048
#define EE 512
#define HH 8
#define DD 64
#define MM (BB * LL)   // 4096
#define LW (LL / 64)   // 32 k-tiles of 64

typedef short bf16x8 __attribute__((ext_vector_type(8)));   // 8 bf16 = 4 VGPRs
typedef float f32x4 __attribute__((ext_vector_type(4)));

#define MFMA16(a, b, c) __builtin_amdgcn_mfma_f32_16x16x32_bf16((a), (b), (c), 0, 0, 0)

#if __has_builtin(__builtin_amdgcn_exp2f)
#define EXP2(x) __builtin_amdgcn_exp2f(x)
#else
#define EXP2(x) exp2f(x)
#endif

// q-scale with log2(e) folded: (1/sqrt(512)) * log2(e)
#define QSCALE 0.0637587146f

// async global->LDS, 16B per lane; LDS dest = wave-uniform base + lane*16B
__device__ __forceinline__ void gl2lds16(const __hip_bfloat16* g, __hip_bfloat16* l) {
    __builtin_amdgcn_global_load_lds(
        (const __attribute__((address_space(1))) unsigned int*)(g),
        (__attribute__((address_space(3))) unsigned int*)(l),
        16, 0, 0);
}

__device__ __forceinline__ uint4 cvt8_bf16(const float4 a, const float4 b) {
    union { __hip_bfloat16 h[8]; uint4 u; } t;
    t.h[0] = __float2bfloat16(a.x); t.h[1] = __float2bfloat16(a.y);
    t.h[2] = __float2bfloat16(a.z); t.h[3] = __float2bfloat16(a.w);
    t.h[4] = __float2bfloat16(b.x); t.h[5] = __float2bfloat16(b.y);
    t.h[6] = __float2bfloat16(b.z); t.h[7] = __float2bfloat16(b.w);
    return t.u;
}

// ---------------------------------------------------------------------------
// prep: X cvt (3072 blks), W cvt (512 blks), mask ballot grid-strided:
// 2048 blks x 16 rounds x 256 thr = 8,388,608 = BB*LL*LL exactly.
// ---------------------------------------------------------------------------
struct PrepArgs {
    const float* xsrc[3];
    __hip_bfloat16* xdst[3];
    const float* wsrc[4];
    __hip_bfloat16* wdst[4];
    const int* mask;
    unsigned long long* mbits;
};

__global__ __launch_bounds__(256) void prep(PrepArgs a) {
    const int blk = blockIdx.x;
    if (blk < 3072) {
        const int t = blk >> 10;
        const int i = ((blk & 1023) * 256 + threadIdx.x) * 8;
        const float* s = a.xsrc[t] + i;
        float4 f0 = *(const float4*)(s);
        float4 f1 = *(const float4*)(s + 4);
        *(uint4*)(a.xdst[t] + i) = cvt8_bf16(f0, f1);
    } else if (blk < 3584) {
        const int r = blk - 3072;
        const int t = r >> 7;
        const int i = ((r & 127) * 256 + threadIdx.x) * 8;
        const float* s = a.wsrc[t] + i;
        float4 f0 = *(const float4*)(s);
        float4 f1 = *(const float4*)(s + 4);
        *(uint4*)(a.wdst[t] + i) = cvt8_bf16(f0, f1);
    } else {
        const int mb = blk - 3584;   // 0..2047, 16 rounds each
        #pragma unroll
        for (int r = 0; r < 16; ++r) {
            const size_t idx = ((size_t)mb * 16 + r) * 256 + threadIdx.x;
            const int m = a.mask[idx];
            const unsigned long long w = __ballot(m != 0);
            if ((threadIdx.x & 63) == 0) a.mbits[idx >> 6] = w;
        }
    }
}

// ---------------------------------------------------------------------------
// bf16 GEMM, tile 64(M) x 128(N), BK=64, 4 waves (each M64 x N32: 4x2 frags,
// 16 MFMA/iter). LDS double-buffered via global_load_lds w=16 into unpadded
// [buf][khalf][rows][32]. One barrier per iter. r7 structure (best measured).
// z==0: q output with QSCALE folded.  z==2: writes V^T [B,H,D,L] DIRECTLY
// from accumulators (4 consecutive l per reg -> 8B stores), replacing the
// separate transpose kernel.
// ---------------------------------------------------------------------------
struct QKVArgs {
    const __hip_bfloat16* X[3];
    const __hip_bfloat16* W[3];
    const float* bias[3];
    __hip_bfloat16* O[3];   // O[2] = vtg (transposed layout)
};

__global__ __launch_bounds__(256) void gemm_qkv(QKVArgs p) {
    __shared__ __hip_bfloat16 As[2][2][64][32];    // 16KB
    __shared__ __hip_bfloat16 Bs[2][2][128][32];   // 32KB

    const int z = blockIdx.z;
    const __hip_bfloat16* __restrict__ X = p.X[z];
    const __hip_bfloat16* __restrict__ W = p.W[z];
    const float* __restrict__ bias = p.bias[z];
    __hip_bfloat16* __restrict__ O = p.O[z];

    const int tid = threadIdx.x;
    const int wave = tid >> 6, lane = tid & 63;
    const int l15 = lane & 15, quad = lane >> 4;
    const int wn = wave * 32;
    const int m0 = blockIdx.y * 64, n0 = blockIdx.x * 128;

    const int lr = lane >> 2;          // 0..15
    const int lc = (lane & 3) * 8;
    const __hip_bfloat16* Ax = X + (size_t)(m0 + wave * 16 + lr) * EE + lc;
    const __hip_bfloat16* Bx = W + (size_t)(n0 + wave * 32 + lr) * EE + lc;

    f32x4 acc[4][2] = {};

    #define STAGE_G(buf, k0)                                                   \
        gl2lds16(Ax + (k0),           &As[buf][0][wave * 16][0]);              \
        gl2lds16(Ax + (k0) + 32,      &As[buf][1][wave * 16][0]);              \
        gl2lds16(Bx + (k0),           &Bs[buf][0][wave * 32][0]);              \
        gl2lds16(Bx + (k0) + 32,      &Bs[buf][1][wave * 32][0]);              \
        gl2lds16(Bx + (k0) + 16 * EE,      &Bs[buf][0][wave * 32 + 16][0]);    \
        gl2lds16(Bx + (k0) + 16 * EE + 32, &Bs[buf][1][wave * 32 + 16][0]);

    STAGE_G(0, 0);
    __syncthreads();

    for (int kt = 0; kt < 8; ++kt) {
        const int cur = kt & 1;
        if (kt < 7) { STAGE_G(cur ^ 1, (kt + 1) * 64); }

        #pragma unroll
        for (int c = 0; c < 2; ++c) {
            bf16x8 af[4], bf2[2];
            #pragma unroll
            for (int i = 0; i < 4; ++i)
                af[i] = *(const bf16x8*)&As[cur][c][i * 16 + l15][quad * 8];
            #pragma unroll
            for (int j = 0; j < 2; ++j)
                bf2[j] = *(const bf16x8*)&Bs[cur][c][wn + j * 16 + l15][quad * 8];
            #pragma unroll
            for (int i = 0; i < 4; ++i)
                #pragma unroll
                for (int j = 0; j < 2; ++j)
                    acc[i][j] = MFMA16(af[i], bf2[j], acc[i][j]);
        }
        __syncthreads();
    }

    if (z == 2) {
        // V^T write: vtg[((b*HH+h)*DD+d)*LL + l], 4 consecutive l per store
        #pragma unroll
        for (int i = 0; i < 4; ++i)
            #pragma unroll
            for (int j = 0; j < 2; ++j) {
                const int n = n0 + wn + j * 16 + l15;
                const float bv = bias[n];
                const int h = n >> 6, d = n & 63;
                union { __hip_bfloat16 hh[4]; ushort4 v4; } pk;
                #pragma unroll
                for (int reg = 0; reg < 4; ++reg)
                    pk.hh[reg] = __float2bfloat16(acc[i][j][reg] + bv);
                const int m = m0 + i * 16 + quad * 4;   // 4 consecutive l
                const int bb = m >> 11, l = m & 2047;
                *(ushort4*)&O[(((size_t)bb * HH + h) * DD + d) * LL + l] = pk.v4;
            }
    } else {
        const float oscale = (z == 0) ? QSCALE : 1.0f;
        #pragma unroll
        for (int i = 0; i < 4; ++i)
            #pragma unroll
            for (int j = 0; j < 2; ++j) {
                const int n = n0 + wn + j * 16 + l15;
                const float bv = bias[n];
                #pragma unroll
                for (int reg = 0; reg < 4; ++reg) {
                    const int m = m0 + i * 16 + quad * 4 + reg;
                    O[(size_t)m * EE + n] = __float2bfloat16((acc[i][j][reg] + bv) * oscale);
                }
            }
    }
}

__global__ __launch_bounds__(256) void gemm_out(
    const __hip_bfloat16* __restrict__ X, const __hip_bfloat16* __restrict__ W,
    const float* __restrict__ bias, float* __restrict__ C) {
    __shared__ __hip_bfloat16 As[2][2][64][32];
    __shared__ __hip_bfloat16 Bs[2][2][128][32];

    const int tid = threadIdx.x;
    const int wave = tid >> 6, lane = tid & 63;
    const int l15 = lane & 15, quad = lane >> 4;
    const int wn = wave * 32;
    const int m0 = blockIdx.y * 64, n0 = blockIdx.x * 128;

    const int lr = lane >> 2;
    const int lc = (lane & 3) * 8;
    const __hip_bfloat16* Ax = X + (size_t)(m0 + wave * 16 + lr) * EE + lc;
    const __hip_bfloat16* Bx = W + (size_t)(n0 + wave * 32 + lr) * EE + lc;

    f32x4 acc[4][2] = {};

    STAGE_G(0, 0);
    __syncthreads();

    for (int kt = 0; kt < 8; ++kt) {
        const int cur = kt & 1;
        if (kt < 7) { STAGE_G(cur ^ 1, (kt + 1) * 64); }

        #pragma unroll
        for (int c = 0; c < 2; ++c) {
            bf16x8 af[4], bf2[2];
            #pragma unroll
            for (int i = 0; i < 4; ++i)
                af[i] = *(const bf16x8*)&As[cur][c][i * 16 + l15][quad * 8];
            #pragma unroll
            for (int j = 0; j < 2; ++j)
                bf2[j] = *(const bf16x8*)&Bs[cur][c][wn + j * 16 + l15][quad * 8];
            #pragma unroll
            for (int i = 0; i < 4; ++i)
                #pragma unroll
                for (int j = 0; j < 2; ++j)
                    acc[i][j] = MFMA16(af[i], bf2[j], acc[i][j]);
        }
        __syncthreads();
    }

    #pragma unroll
    for (int i = 0; i < 4; ++i)
        #pragma unroll
        for (int j = 0; j < 2; ++j) {
            const int n = n0 + wn + j * 16 + l15;
            const float bv = bias[n];
            #pragma unroll
            for (int reg = 0; reg < 4; ++reg) {
                const int m = m0 + i * 16 + quad * 4 + reg;
                C[(size_t)m * EE + n] = acc[i][j][reg] + bv;
            }
        }
}

// ---------------------------------------------------------------------------
// Flash attention (r8 structure: conflicts=0). bf16 MFMA, S^T = K Q^T,
// no-max softmax with exp2 (log2e folded into q). Register-prefetch
// double-buffered K/V. All LDS strides 68 (34 dwords, gcd 2 -> free).
// Packed bf16 conversion for P.
// ---------------------------------------------------------------------------
__global__ __launch_bounds__(256) void attn_mfma(
    const __hip_bfloat16* __restrict__ Qb, const __hip_bfloat16* __restrict__ Kb,
    const __hip_bfloat16* __restrict__ vtg, const unsigned long long* __restrict__ mbits,
    __hip_bfloat16* __restrict__ Op) {
    __shared__ __hip_bfloat16 Ks[2][64][68];
    __shared__ __hip_bfloat16 Vs[2][64][68];
    __shared__ __hip_bfloat16 Ps[4][16][68];

    const int tid = threadIdx.x;
    const int wave = tid >> 6;
    const int lane = tid & 63;
    const int l15 = lane & 15;
    const int quad = lane >> 4;
    const int b = blockIdx.z;
    const int h = blockIdx.y;
    const int q0 = blockIdx.x * 64;
    const int myq = q0 + wave * 16 + l15;

    const int srow = tid >> 2;        // 0..63
    const int scg = (tid & 3) * 16;   // 0,16,32,48

    bf16x8 qf[2];
    {
        const __hip_bfloat16* qrow = Qb + ((size_t)b * LL + myq) * EE + h * DD;
        qf[0] = *(const bf16x8*)(qrow + quad * 8);
        qf[1] = *(const bf16x8*)(qrow + 32 + quad * 8);
    }

    const __hip_bfloat16* kbase = Kb + ((size_t)b * LL + srow) * EE + h * DD + scg;
    const __hip_bfloat16* vbase = vtg + (((size_t)b * HH + h) * DD + srow) * LL + scg;
    const unsigned long long* mrow = mbits + ((size_t)b * LL + myq) * LW;

    f32x4 o[4] = {};
    float lrun = 0.f;

    {
        uint4 k0a = *(const uint4*)(kbase);
        uint4 k0b = *(const uint4*)(kbase + 8);
        uint4 v0a = *(const uint4*)(vbase);
        uint4 v0b = *(const uint4*)(vbase + 8);
        *(uint4*)&Ks[0][srow][scg] = k0a;
        *(uint4*)&Ks[0][srow][scg + 8] = k0b;
        *(uint4*)&Vs[0][srow][scg] = v0a;
        *(uint4*)&Vs[0][srow][scg + 8] = v0b;
    }
    unsigned long long mw_cur = mrow[0];
    __syncthreads();

    for (int t = 0; t < LW; ++t) {
        const int cur = t & 1;
        const int nxt = cur ^ 1;
        const bool more = (t + 1) < LW;

        uint4 ka0, ka1, va0, va1;
        unsigned long long mw_n;
        if (more) {
            const __hip_bfloat16* kn = kbase + (size_t)(t + 1) * 64 * EE;
            const __hip_bfloat16* vn = vbase + (t + 1) * 64;
            ka0 = *(const uint4*)(kn);
            ka1 = *(const uint4*)(kn + 8);
            va0 = *(const uint4*)(vn);
            va1 = *(const uint4*)(vn + 8);
            mw_n = mrow[t + 1];
        }

        // ---- S^T = K (Q*scale*log2e)^T ----
        f32x4 st[4] = {};
        #pragma unroll
        for (int mt = 0; mt < 4; ++mt) {
            bf16x8 a0 = *(const bf16x8*)&Ks[cur][mt * 16 + l15][quad * 8];
            bf16x8 a1 = *(const bf16x8*)&Ks[cur][mt * 16 + l15][32 + quad * 8];
            st[mt] = MFMA16(a0, qf[0], st[mt]);
            st[mt] = MFMA16(a1, qf[1], st[mt]);
        }

        // ---- no-max softmax: p = live ? exp2(logit) : 0 ----
        #pragma unroll
        for (int mt = 0; mt < 4; ++mt) {
            float p[4];
            #pragma unroll
            for (int reg = 0; reg < 4; ++reg) {
                const bool live = (mw_cur >> (mt * 16 + quad * 4 + reg)) & 1ull;
                const float e = EXP2(st[mt][reg]);
                p[reg] = live ? e : 0.f;
                lrun += p[reg];
            }
            union { __hip_bfloat162 h2[2]; ushort4 v; } pk;
            pk.h2[0] = __float22bfloat162_rn(make_float2(p[0], p[1]));
            pk.h2[1] = __float22bfloat162_rn(make_float2(p[2], p[3]));
            *(ushort4*)&Ps[wave][l15][mt * 16 + quad * 4] = pk.v;
        }

        // ---- O += P V (wave-private strip, no barrier) ----
        bf16x8 pa0 = *(const bf16x8*)&Ps[wave][l15][quad * 8];
        bf16x8 pa1 = *(const bf16x8*)&Ps[wave][l15][32 + quad * 8];
        #pragma unroll
        for (int nt = 0; nt < 4; ++nt) {
            bf16x8 vb0 = *(const bf16x8*)&Vs[cur][nt * 16 + l15][quad * 8];
            bf16x8 vb1 = *(const bf16x8*)&Vs[cur][nt * 16 + l15][32 + quad * 8];
            o[nt] = MFMA16(pa0, vb0, o[nt]);
            o[nt] = MFMA16(pa1, vb1, o[nt]);
        }

        if (more) {
            *(uint4*)&Ks[nxt][srow][scg] = ka0;
            *(uint4*)&Ks[nxt][srow][scg + 8] = ka1;
            *(uint4*)&Vs[nxt][srow][scg] = va0;
            *(uint4*)&Vs[nxt][srow][scg + 8] = va1;
            mw_cur = mw_n;
        }
        __syncthreads();
    }

    lrun += __shfl_xor(lrun, 16);
    lrun += __shfl_xor(lrun, 32);
    const float linv = 1.f / lrun;
    float linvR[4];
    #pragma unroll
    for (int reg = 0; reg < 4; ++reg)
        linvR[reg] = __shfl(linv, quad * 4 + reg);

    __hip_bfloat16* Ob = Op + ((size_t)b * LL + q0 + wave * 16) * EE + h * DD;
    #pragma unroll
    for (int nt = 0; nt < 4; ++nt)
        #pragma unroll
        for (int reg = 0; reg < 4; ++reg) {
            const int qrow = quad * 4 + reg;
            Ob[(size_t)qrow * EE + nt * 16 + l15] =
                __float2bfloat16(o[nt][reg] * linvR[reg]);
        }
}

// ---------------------------------------------------------------------------
extern "C" void kernel_launch(void* const* d_in, const int* in_sizes, int n_in,
                              void* d_out, int out_size, void* d_ws, size_t ws_size,
                              hipStream_t stream) {
    const float* values = (const float*)d_in[0];
    const float* keys   = (const float*)d_in[1];
    const float* query  = (const float*)d_in[2];
    const int*   mask   = (const int*)d_in[3];
    const float* Wv = (const float*)d_in[4];
    const float* bv = (const float*)d_in[5];
    const float* Wk = (const float*)d_in[6];
    const float* bk = (const float*)d_in[7];
    const float* Wq = (const float*)d_in[8];
    const float* bq = (const float*)d_in[9];
    const float* Wo = (const float*)d_in[10];
    const float* bo = (const float*)d_in[11];
    float* out = (float*)d_out;

    const size_t XS = (size_t)MM * EE * 2;   // 4 MB bf16 [4096,512]
    const size_t WS = (size_t)EE * EE * 2;   // 0.5 MB bf16 [512,512]
    char* w = (char*)d_ws;
    __hip_bfloat16* xq  = (__hip_bfloat16*)(w);
    __hip_bfloat16* xk  = (__hip_bfloat16*)(w + XS);
    __hip_bfloat16* xv  = (__hip_bfloat16*)(w + 2 * XS);
    __hip_bfloat16* qb  = (__hip_bfloat16*)(w + 3 * XS);
    __hip_bfloat16* kb  = (__hip_bfloat16*)(w + 4 * XS);
    __hip_bfloat16* vtg = (__hip_bfloat16*)(w + 5 * XS);
    __hip_bfloat16* aob = (__hip_bfloat16*)(w + 6 * XS);
    __hip_bfloat16* wqb = (__hip_bfloat16*)(w + 7 * XS);
    __hip_bfloat16* wkb = (__hip_bfloat16*)(w + 7 * XS + WS);
    __hip_bfloat16* wvb = (__hip_bfloat16*)(w + 7 * XS + 2 * WS);
    __hip_bfloat16* wob = (__hip_bfloat16*)(w + 7 * XS + 3 * WS);
    unsigned long long* mbits = (unsigned long long*)(w + 7 * XS + 4 * WS);

    PrepArgs pa;
    pa.xsrc[0] = query; pa.xsrc[1] = keys; pa.xsrc[2] = values;
    pa.xdst[0] = xq;    pa.xdst[1] = xk;   pa.xdst[2] = xv;
    pa.wsrc[0] = Wq; pa.wsrc[1] = Wk; pa.wsrc[2] = Wv; pa.wsrc[3] = Wo;
    pa.wdst[0] = wqb; pa.wdst[1] = wkb; pa.wdst[2] = wvb; pa.wdst[3] = wob;
    pa.mask = mask; pa.mbits = mbits;

    QKVArgs qa;
    qa.X[0] = xq;  qa.X[1] = xk;  qa.X[2] = xv;
    qa.W[0] = wqb; qa.W[1] = wkb; qa.W[2] = wvb;
    qa.bias[0] = bq; qa.bias[1] = bk; qa.bias[2] = bv;
    qa.O[0] = qb;  qa.O[1] = kb;  qa.O[2] = vtg;   // z==2 writes V^T directly

    prep<<<5632, 256, 0, stream>>>(pa);
    gemm_qkv<<<dim3(EE / 128, MM / 64, 3), 256, 0, stream>>>(qa);
    attn_mfma<<<dim3(LL / 64, HH, BB), 256, 0, stream>>>(qb, kb, vtg, mbits, aob);
    gemm_out<<<dim3(EE / 128, MM / 64), 256, 0, stream>>>(aob, wob, bo, out);
}